// Round 1
// baseline (2435.718 us; speedup 1.0000x reference)
//
#include <hip/hip_runtime.h>
#include <cfloat>

#define N_ROWS 65536
#define DIM    256
#define KCODES 4096
#define TILE_R 32
#define CHUNK_C 256
#define KSLICE 32

__global__ __launch_bounds__(256, 2)
void vq_argmin_kernel(const float* __restrict__ x, const float* __restrict__ cb,
                      float* __restrict__ out_q, float* __restrict__ out_idx) {
    __shared__ float As[TILE_R * DIM];      // 32 KB, x tile resident
    __shared__ float Bs[KSLICE * CHUNK_C];  // 32 KB, codebook k-slice (transposed+swizzled)

    const int t  = threadIdx.x;
    const int tx = t & 63;          // col group: cols 4*tx..4*tx+3
    const int ty = t >> 6;          // row group: rows 8*ty..8*ty+7 (wave == one ty)
    const int n0 = blockIdx.x * TILE_R;

    // ---- Phase 1: stage x tile (coalesced float4, conflict-free LDS writes) ----
    #pragma unroll
    for (int i = 0; i < 8; ++i) {
        int r  = 4 * i + (t >> 6);
        int d4 = (t & 63) * 4;
        *(float4*)&As[r * DIM + d4] = *(const float4*)&x[(size_t)(n0 + r) * DIM + d4];
    }
    __syncthreads();

    // ---- Phase 2: x_sq per row, fp64 accumulate -> fp32 (Bs as scratch) ----
    double* dtmp = (double*)Bs;                   // 128 doubles = bytes [0,1024)
    if (t < TILE_R * 4) {
        int r = t >> 2, part = t & 3;
        const float* ap = &As[r * DIM + 64 * part];
        double s = 0.0;
        for (int k = 0; k < 64; ++k) { double v = (double)ap[k]; s = fma(v, v, s); }
        dtmp[t] = s;
    }
    __syncthreads();
    float* xf = (float*)Bs + 512;                 // bytes [2048,2176), disjoint from dtmp
    if (t < TILE_R) {
        double s = (dtmp[4*t] + dtmp[4*t+1]) + (dtmp[4*t+2] + dtmp[4*t+3]);
        xf[t] = (float)s;
    }
    __syncthreads();
    float xsq_r[8];
    #pragma unroll
    for (int j = 0; j < 8; ++j) xsq_r[j] = xf[8 * ty + j];
    // next __syncthreads (top of slice loop) protects Bs before reuse

    float best[8]; int bidx[8];
    #pragma unroll
    for (int j = 0; j < 8; ++j) { best[j] = FLT_MAX; bidx[j] = 0; }

    for (int chunk = 0; chunk < KCODES / CHUNK_C; ++chunk) {
        const int c0 = chunk * CHUNK_C;
        float acc[8][4];
        #pragma unroll
        for (int j = 0; j < 8; ++j) {
            acc[j][0] = 0.f; acc[j][1] = 0.f; acc[j][2] = 0.f; acc[j][3] = 0.f;
        }
        float csq[4] = {0.f, 0.f, 0.f, 0.f};

        for (int sl = 0; sl < DIM / KSLICE; ++sl) {
            const int ks = sl * KSLICE;
            __syncthreads();   // prior slice fully consumed
            // stage codebook slice transposed, rotate swizzle phys_c=(c+4k)&255
            {
                const int cl = t & 31, q = t >> 5;   // q in 0..7 across block
                #pragma unroll
                for (int i = 0; i < 8; ++i) {
                    int c_loc = 32 * i + cl;
                    float4 v = *(const float4*)&cb[(size_t)(c0 + c_loc) * DIM + ks + 4 * q];
                    int kk = 4 * q;
                    Bs[(kk+0) * CHUNK_C + ((c_loc + 4*(kk+0)) & 255)] = v.x;
                    Bs[(kk+1) * CHUNK_C + ((c_loc + 4*(kk+1)) & 255)] = v.y;
                    Bs[(kk+2) * CHUNK_C + ((c_loc + 4*(kk+2)) & 255)] = v.z;
                    Bs[(kk+3) * CHUNK_C + ((c_loc + 4*(kk+3)) & 255)] = v.w;
                }
            }
            __syncthreads();
            // compute 32 k-steps: 8 rows x 4 cols per thread + fused csq
            #pragma unroll
            for (int kb = 0; kb < 8; ++kb) {
                float4 a[8];
                #pragma unroll
                for (int j = 0; j < 8; ++j)   // broadcast reads (wave-uniform)
                    a[j] = *(const float4*)&As[(8 * ty + j) * DIM + ks + 4 * kb];
                #pragma unroll
                for (int u = 0; u < 4; ++u) {
                    int kk = 4 * kb + u;
                    float4 b = *(const float4*)&Bs[kk * CHUNK_C + ((4 * tx + 4 * kk) & 255)];
                    csq[0] = fmaf(b.x, b.x, csq[0]);
                    csq[1] = fmaf(b.y, b.y, csq[1]);
                    csq[2] = fmaf(b.z, b.z, csq[2]);
                    csq[3] = fmaf(b.w, b.w, csq[3]);
                    #pragma unroll
                    for (int j = 0; j < 8; ++j) {
                        float av = (u == 0) ? a[j].x : (u == 1) ? a[j].y : (u == 2) ? a[j].z : a[j].w;
                        acc[j][0] = fmaf(av, b.x, acc[j][0]);
                        acc[j][1] = fmaf(av, b.y, acc[j][1]);
                        acc[j][2] = fmaf(av, b.z, acc[j][2]);
                        acc[j][3] = fmaf(av, b.w, acc[j][3]);
                    }
                }
            }
        }
        // epilogue: dist = (x_sq - 2*dot) + c_sq, exact reference rounding
        #pragma unroll
        for (int j = 0; j < 8; ++j) {
            #pragma unroll
            for (int cc = 0; cc < 4; ++cc) {
                float d = fmaf(-2.f, acc[j][cc], xsq_r[j]) + csq[cc];
                int c = c0 + 4 * tx + cc;
                if (d < best[j]) { best[j] = d; bidx[j] = c; }   // strict <: first index wins
            }
        }
    }

    __syncthreads();   // all Bs reads done before reuse as idx store
    int* idxs = (int*)Bs;
    #pragma unroll
    for (int j = 0; j < 8; ++j) {
        float v = best[j]; int idx = bidx[j];
        #pragma unroll
        for (int off = 1; off < 64; off <<= 1) {
            float v2 = __shfl_xor(v, off);
            int  i2 = __shfl_xor(idx, off);
            if (v2 < v || (v2 == v && i2 < idx)) { v = v2; idx = i2; }
        }
        if (tx == 0) idxs[8 * ty + j] = idx;
    }
    __syncthreads();

    // indices out (as float32, per harness flat-float output layout)
    if (t < TILE_R) out_idx[n0 + t] = (float)idxs[t];

    // gather winners: coalesced float4 copy from codebook
    #pragma unroll
    for (int i = 0; i < 8; ++i) {
        int r  = 4 * i + (t >> 6);
        int d4 = (t & 63) * 4;
        *(float4*)&out_q[(size_t)(n0 + r) * DIM + d4] =
            *(const float4*)&cb[(size_t)idxs[r] * DIM + d4];
    }
}

extern "C" void kernel_launch(void* const* d_in, const int* in_sizes, int n_in,
                              void* d_out, int out_size, void* d_ws, size_t ws_size,
                              hipStream_t stream) {
    const float* x  = (const float*)d_in[0];
    const float* cb = (const float*)d_in[1];
    float* out_q   = (float*)d_out;                          // N*DIM quantized
    float* out_idx = (float*)d_out + (size_t)N_ROWS * DIM;   // N indices as float
    dim3 grid(N_ROWS / TILE_R), block(256);
    vq_argmin_kernel<<<grid, block, 0, stream>>>(x, cb, out_q, out_idx);
}

// Round 2
// 635.131 us; speedup vs baseline: 3.8350x; 3.8350x over previous
//
#include <hip/hip_runtime.h>
#include <cfloat>

typedef _Float16 half8 __attribute__((ext_vector_type(8)));
typedef float    f32x4 __attribute__((ext_vector_type(4)));

#define N_ROWS 65536
#define DIM    256
#define KCODES 4096
#define BM 128
#define BN 128
#define BK 32

// d_ws layout (bytes): csq[4096]f32 | xsq[65536]f32 | ch[1M]f16 | cl[1M]f16  = 4.27 MB
#define WS_CSQ 0
#define WS_XSQ 16384
#define WS_CH  278528
#define WS_CL  2375680

// ---- Prologue 1: csq (k-ascending fmaf chain, matches np per round 1) + cb -> f16 hi/lo (x64) ----
__global__ void prep_codes(const float* __restrict__ cb, float* __restrict__ csq,
                           _Float16* __restrict__ ch, _Float16* __restrict__ cl) {
    int c = blockIdx.x * blockDim.x + threadIdx.x;
    if (c >= KCODES) return;
    const float* row = cb + (size_t)c * DIM;
    float s = 0.f;
    for (int k = 0; k < DIM; k += 4) {
        float4 v = *(const float4*)&row[k];
        s = fmaf(v.x, v.x, s); s = fmaf(v.y, v.y, s);
        s = fmaf(v.z, v.z, s); s = fmaf(v.w, v.w, s);
        float sv[4] = {v.x * 64.f, v.y * 64.f, v.z * 64.f, v.w * 64.f};
        #pragma unroll
        for (int j = 0; j < 4; ++j) {
            _Float16 h = (_Float16)sv[j];
            ch[(size_t)c * DIM + k + j] = h;
            cl[(size_t)c * DIM + k + j] = (_Float16)(sv[j] - (float)h);
        }
    }
    csq[c] = s;
}

// ---- Prologue 2: xsq via fp64 (matched ref in round 1) ----
__global__ void prep_xsq(const float* __restrict__ x, float* __restrict__ xsq) {
    __shared__ float  As[32 * DIM];
    __shared__ double dtmp[128];
    const int t = threadIdx.x;
    const int n0 = blockIdx.x * 32;
    #pragma unroll
    for (int i = 0; i < 8; ++i) {
        int r = 4 * i + (t >> 6), d4 = (t & 63) * 4;
        *(float4*)&As[r * DIM + d4] = *(const float4*)&x[(size_t)(n0 + r) * DIM + d4];
    }
    __syncthreads();
    if (t < 128) {
        int r = t >> 2, part = t & 3;
        const float* ap = &As[r * DIM + 64 * part];
        double s = 0.0;
        for (int k = 0; k < 64; ++k) { double v = (double)ap[k]; s = fma(v, v, s); }
        dtmp[t] = s;
    }
    __syncthreads();
    if (t < 32)
        xsq[n0 + t] = (float)((dtmp[4*t] + dtmp[4*t+1]) + (dtmp[4*t+2] + dtmp[4*t+3]));
}

// ---- Main: 3-split f16 MFMA GEMM + fused argmin ----
// LDS layout per tile row (32 f16): 4 granules of 8 f16; phys granule = g ^ (row&3)  (<=2-way, free)
__global__ __launch_bounds__(256, 2)
void vq_mfma(const float* __restrict__ x, const float* __restrict__ cb,
             const float* __restrict__ csq, const float* __restrict__ xsq,
             const _Float16* __restrict__ ch, const _Float16* __restrict__ cl,
             float* __restrict__ out_q, float* __restrict__ out_idx) {
    __shared__ _Float16 AhS[BM * BK], AlS[BM * BK], BhS[BN * BK], BlS[BN * BK]; // 4x8KB

    const int t = threadIdx.x;
    const int lane = t & 63, wave = t >> 6;
    const int wy = wave >> 1, wx = wave & 1;
    const int m = lane & 15, q = lane >> 4;   // MFMA: A/B row = m, k-granule = q; C: row=4q+e, col=m
    const int n0 = blockIdx.x * BM;
    const int sr = t >> 1, sh = t & 1;        // staging: row 0..127, k-half 0..1
    const int swz = (q ^ (m & 3)) * 8;        // frag-read granule offset (f16 units)

    float xsq_r[16];
    #pragma unroll
    for (int s = 0; s < 16; ++s)
        xsq_r[s] = xsq[n0 + 64 * wy + 16 * (s >> 2) + 4 * q + (s & 3)];

    float best[16]; int bidx[16];
    #pragma unroll
    for (int s = 0; s < 16; ++s) { best[s] = FLT_MAX; bidx[s] = 0; }

    for (int chunk = 0; chunk < KCODES / BN; ++chunk) {
        const int c0 = chunk * BN;
        float csq_c[4];
        #pragma unroll
        for (int tc = 0; tc < 4; ++tc) csq_c[tc] = csq[c0 + 64 * wx + 16 * tc + m];

        f32x4 acc[4][4];
        #pragma unroll
        for (int tr = 0; tr < 4; ++tr)
            #pragma unroll
            for (int tc = 0; tc < 4; ++tc) acc[tr][tc] = (f32x4){0.f, 0.f, 0.f, 0.f};

        for (int sl = 0; sl < DIM / BK; ++sl) {
            const int ks = sl * BK;
            __syncthreads();
            // stage A slice: rows n0..+127, k ks+16*sh..+15 (fp32 -> f16 hi/lo)
            {
                const float* asrc = &x[(size_t)(n0 + sr) * DIM + ks + 16 * sh];
                float av[16];
                *(float4*)&av[0]  = *(const float4*)(asrc + 0);
                *(float4*)&av[4]  = *(const float4*)(asrc + 4);
                *(float4*)&av[8]  = *(const float4*)(asrc + 8);
                *(float4*)&av[12] = *(const float4*)(asrc + 12);
                half8 h0, h1, l0, l1;
                #pragma unroll
                for (int j = 0; j < 8; ++j) {
                    _Float16 h = (_Float16)av[j];
                    h0[j] = h; l0[j] = (_Float16)(av[j] - (float)h);
                    _Float16 g = (_Float16)av[j + 8];
                    h1[j] = g; l1[j] = (_Float16)(av[j + 8] - (float)g);
                }
                const int base = sr * BK, sw = sr & 3;
                const int g0 = 2 * sh, g1 = 2 * sh + 1;
                *(half8*)&AhS[base + ((g0 ^ sw) * 8)] = h0;
                *(half8*)&AhS[base + ((g1 ^ sw) * 8)] = h1;
                *(half8*)&AlS[base + ((g0 ^ sw) * 8)] = l0;
                *(half8*)&AlS[base + ((g1 ^ sw) * 8)] = l1;
            }
            // stage B slice from pre-converted ch/cl
            {
                const _Float16* bhs = &ch[(size_t)(c0 + sr) * DIM + ks + 16 * sh];
                const _Float16* bls = &cl[(size_t)(c0 + sr) * DIM + ks + 16 * sh];
                half8 h0 = *(const half8*)(bhs), h1 = *(const half8*)(bhs + 8);
                half8 l0 = *(const half8*)(bls), l1 = *(const half8*)(bls + 8);
                const int base = sr * BK, sw = sr & 3;
                const int g0 = 2 * sh, g1 = 2 * sh + 1;
                *(half8*)&BhS[base + ((g0 ^ sw) * 8)] = h0;
                *(half8*)&BhS[base + ((g1 ^ sw) * 8)] = h1;
                *(half8*)&BlS[base + ((g0 ^ sw) * 8)] = l0;
                *(half8*)&BlS[base + ((g1 ^ sw) * 8)] = l1;
            }
            __syncthreads();

            half8 aH[4], aL[4], bH[4], bL[4];
            #pragma unroll
            for (int tr = 0; tr < 4; ++tr) {
                int off = (64 * wy + 16 * tr + m) * BK + swz;
                aH[tr] = *(const half8*)&AhS[off];
                aL[tr] = *(const half8*)&AlS[off];
            }
            #pragma unroll
            for (int tc = 0; tc < 4; ++tc) {
                int off = (64 * wx + 16 * tc + m) * BK + swz;
                bH[tc] = *(const half8*)&BhS[off];
                bL[tc] = *(const half8*)&BlS[off];
            }
            // 3 product sweeps, reuse distance 16 for full MFMA ILP
            #pragma unroll
            for (int tc = 0; tc < 4; ++tc)
                #pragma unroll
                for (int tr = 0; tr < 4; ++tr)
                    acc[tr][tc] = __builtin_amdgcn_mfma_f32_16x16x32_f16(aH[tr], bH[tc], acc[tr][tc], 0, 0, 0);
            #pragma unroll
            for (int tc = 0; tc < 4; ++tc)
                #pragma unroll
                for (int tr = 0; tr < 4; ++tr)
                    acc[tr][tc] = __builtin_amdgcn_mfma_f32_16x16x32_f16(aH[tr], bL[tc], acc[tr][tc], 0, 0, 0);
            #pragma unroll
            for (int tc = 0; tc < 4; ++tc)
                #pragma unroll
                for (int tr = 0; tr < 4; ++tr)
                    acc[tr][tc] = __builtin_amdgcn_mfma_f32_16x16x32_f16(aL[tr], bH[tc], acc[tr][tc], 0, 0, 0);
        }
        // chunk epilogue: dist + running argmin (cols ascend: tc loop ascending)
        #pragma unroll
        for (int tc = 0; tc < 4; ++tc) {
            int c = c0 + 64 * wx + 16 * tc + m;
            #pragma unroll
            for (int tr = 0; tr < 4; ++tr) {
                #pragma unroll
                for (int e = 0; e < 4; ++e) {
                    float dot = acc[tr][tc][e] * 0.015625f;           // exact /64
                    float d = fmaf(-2.f, dot, xsq_r[tr * 4 + e]) + csq_c[tc];
                    int s = tr * 4 + e;
                    if (d < best[s]) { best[s] = d; bidx[s] = c; }
                }
            }
        }
    }

    // reduce across the 16 lanes of each quad-group (same physical rows)
    #pragma unroll
    for (int s = 0; s < 16; ++s) {
        float v = best[s]; int idx = bidx[s];
        #pragma unroll
        for (int off = 1; off < 16; off <<= 1) {
            float v2 = __shfl_xor(v, off);
            int   i2 = __shfl_xor(idx, off);
            if (v2 < v || (v2 == v && i2 < idx)) { v = v2; idx = i2; }
        }
        best[s] = v; bidx[s] = idx;
    }
    __syncthreads();                      // staging LDS free now
    float* rb = (float*)BhS;              // [row][wx] candidates
    int*   ri = (int*)BlS;
    {
        int s = m;                        // lane writes slot == lane&15 (bijective over rows)
        int row_local = 64 * wy + 16 * (s >> 2) + 4 * q + (s & 3);
        rb[row_local * 2 + wx] = best[s];
        ri[row_local * 2 + wx] = bidx[s];
    }
    __syncthreads();
    int* widx = (int*)AhS;
    if (t < BM) {
        float d0 = rb[t * 2], d1 = rb[t * 2 + 1];
        int   i0 = ri[t * 2], i1 = ri[t * 2 + 1];
        int w = (d1 < d0 || (d1 == d0 && i1 < i0)) ? i1 : i0;
        widx[t] = w;
        out_idx[n0 + t] = (float)w;
    }
    __syncthreads();
    // gather winners, coalesced float4
    const int l4 = t & 63, rg = t >> 6;
    #pragma unroll 4
    for (int i = 0; i < 32; ++i) {
        int r = rg + 4 * i;
        *(float4*)&out_q[(size_t)(n0 + r) * DIM + l4 * 4] =
            *(const float4*)&cb[(size_t)widx[r] * DIM + l4 * 4];
    }
}

extern "C" void kernel_launch(void* const* d_in, const int* in_sizes, int n_in,
                              void* d_out, int out_size, void* d_ws, size_t ws_size,
                              hipStream_t stream) {
    const float* x  = (const float*)d_in[0];
    const float* cb = (const float*)d_in[1];
    float* out_q   = (float*)d_out;
    float* out_idx = (float*)d_out + (size_t)N_ROWS * DIM;

    float*    csq = (float*)((char*)d_ws + WS_CSQ);
    float*    xsq = (float*)((char*)d_ws + WS_XSQ);
    _Float16* ch  = (_Float16*)((char*)d_ws + WS_CH);
    _Float16* cl  = (_Float16*)((char*)d_ws + WS_CL);

    prep_codes<<<KCODES / 256, 256, 0, stream>>>(cb, csq, ch, cl);
    prep_xsq<<<N_ROWS / 32, 256, 0, stream>>>(x, xsq);
    vq_mfma<<<N_ROWS / BM, 256, 0, stream>>>(x, cb, csq, xsq, ch, cl, out_q, out_idx);
}